// Round 3
// baseline (522.054 us; speedup 1.0000x reference)
//
#include <hip/hip_runtime.h>
#include <math.h>

// Problem constants: B=512, N=600, H=256, K=9, WIN=129
#define BB   512
#define NN   600
#define HH   256
#define KS   9
#define WIN  129
#define PADW 4
#define PWIN 137           // WIN + 2*PAD
#define NP   608           // N + 2*PAD
#define ALN_STRIDE 132     // ws stride for per-batch align row

// ---------------- Kernel A: scores + softmax + scatter outputs ----------------
// One block per batch, 1024 threads (16 waves). No min-wave clamp (avoid spills).
__global__ __launch_bounds__(1024) void score_kernel(
    const float* __restrict__ token_keys,   // (B,H,N)
    const int*   __restrict__ num_tokens,   // (B,)
    const float* __restrict__ query,        // (B,H)
    const float* __restrict__ alignment,    // (B,NP)
    const float* __restrict__ cum_align,    // (B,NP)
    const int*   __restrict__ window_start, // (B,)
    const float* __restrict__ conv_w,       // (H,2,K)
    const float* __restrict__ conv_b,       // (H,)
    float* __restrict__ out,
    float* __restrict__ ws_align)           // (B, ALN_STRIDE)
{
  const int b    = blockIdx.x;
  const int t    = threadIdx.x;
  const int lane = t & 63;
  const int wv   = t >> 6;            // 0..15

  __shared__ float sq[HH];
  __shared__ float p0[PWIN], p1[PWIN];
  __shared__ float wred[4 * 19];
  __shared__ float w128red[4];
  __shared__ float sqc[19];
  __shared__ float sS[8][130];
  __shared__ float salign[WIN];
  __shared__ int   cand[WIN];
  __shared__ float s_m, s_sum;
  __shared__ int   s_arg;

  const int ws = window_start[b];
  const int nt = num_tokens[b];
  const float* Kb = token_keys + (size_t)b * (HH * NN);

  // Phase A (waves 0..3): query row, conv fold, w=128 column dot
  if (t < HH) {
    const float q = query[b * HH + t];
    sq[t] = q;
    {
      float acc[19];
      const float* cwp = conv_w + t * 18;
      #pragma unroll
      for (int j = 0; j < 18; ++j) acc[j] = q * cwp[j];
      acc[18] = q * conv_b[t];
      #pragma unroll
      for (int j = 0; j < 19; ++j) {
        float v = acc[j];
        #pragma unroll
        for (int off = 32; off; off >>= 1) v += __shfl_xor(v, off, 64);
        if (lane == 0) wred[wv * 19 + j] = v;
      }
    }
    {
      float v = q * Kb[(size_t)t * NN + ws + 128];
      #pragma unroll
      for (int off = 32; off; off >>= 1) v += __shfl_xor(v, off, 64);
      if (lane == 0) w128red[wv] = v;
    }
  }
  if (t < PWIN) {
    p0[t] = cum_align[b * NP + ws + t] * (1.0f / 1.5f) - 1.0f;
    p1[t] = alignment[b * NP + ws + t] * 2.0f - 1.0f;
  }
  __syncthreads();
  if (t < 19) sqc[t] = wred[t] + wred[19 + t] + wred[38 + t] + wred[57 + t];

  // Phase B: wave v = (hh 0..7, wseg 0..1); 32-long h dot each, coalesced over w
  {
    const int hh   = wv & 7;
    const int wseg = wv >> 3;
    const int w    = wseg * 64 + lane;
    const float* Kp  = Kb + (size_t)(hh * 32) * NN + ws + w;
    const float* sqp = sq + hh * 32;
    float acc = 0.f;
    #pragma unroll 8
    for (int h = 0; h < 32; ++h) acc += sqp[h] * Kp[(size_t)h * NN];
    sS[hh][w] = acc;
  }
  __syncthreads();

  // Score assembly (threads 0..128)
  float sc = 0.f;
  if (t < WIN) {
    float dot;
    if (t < 128) {
      dot = 0.f;
      #pragma unroll
      for (int g = 0; g < 8; ++g) dot += sS[g][t];
    } else {
      dot = w128red[0] + w128red[1] + w128red[2] + w128red[3];
    }
    float f = sqc[18];
    #pragma unroll
    for (int k = 0; k < KS; ++k) f += sqc[k] * p0[t + k] + sqc[9 + k] * p1[t + k];
    sc = (dot + f) * 0.0625f;
    if (ws + t >= nt) sc = -INFINITY;
    salign[t] = sc;
  }
  __syncthreads();

  if (t < 64) {
    float m0 = fmaxf(salign[t], salign[t + 64]);
    if (t == 0) m0 = fmaxf(m0, salign[128]);
    #pragma unroll
    for (int off = 32; off; off >>= 1) m0 = fmaxf(m0, __shfl_xor(m0, off, 64));
    if (t == 0) s_m = m0;
  }
  __syncthreads();
  if (t < WIN) {
    float e = expf(sc - s_m);
    salign[t] = e;
    cand[t] = (sc == s_m) ? t : 0x7fffffff;
  }
  __syncthreads();
  if (t < 64) {
    float s0 = salign[t] + salign[t + 64] + ((t == 0) ? salign[128] : 0.f);
    int   c0 = min(cand[t], cand[t + 64]);
    if (t == 0) c0 = min(c0, cand[128]);
    #pragma unroll
    for (int off = 32; off; off >>= 1) {
      s0 += __shfl_xor(s0, off, 64);
      c0 = min(c0, __shfl_xor(c0, off, 64));
    }
    if (t == 0) { s_sum = s0; s_arg = c0; }
  }
  __syncthreads();

  float* out1 = out + BB * HH;             // unpadded    (B,N)
  float* out2 = out1 + BB * NN;            // full_align  (B,NP)
  float* out3 = out2 + BB * NP;            // cum+align   (B,NP)
  float* out4 = out3 + BB * NP;            // new_start   (B,) as float

  const float inv = 1.0f / s_sum;
  float av = 0.f;
  if (t < WIN) {
    av = salign[t] * inv;
    ws_align[b * ALN_STRIDE + t] = av;     // for the context kernel
  }
  __syncthreads();
  if (t < WIN) salign[t] = av;
  __syncthreads();

  if (t < NN) {
    float v = (t >= ws && t <= ws + 128) ? salign[t - ws] : 0.f;
    out1[b * NN + t] = v;
  }
  if (t < NP) {
    float v = (t >= ws + PADW && t <= ws + PADW + 128) ? salign[t - ws - PADW] : 0.f;
    out2[b * NP + t] = v;
    out3[b * NP + t] = v + cum_align[b * NP + t];
  }
  if (t == 0) {
    int jstar = ws + PADW + s_arg;
    int ns = jstar - (PWIN / 2);
    ns = max(ws, ns);
    ns = min(ns, nt - WIN);
    ns = max(ns, 0);
    out4[b] = (float)ns;
  }
}

// ---------------- Kernel B: context partials ----------------
// Grid (B, 4); block (b, wq) accumulates over its 32/33 w rows. 8192 waves.
__global__ __launch_bounds__(256) void ctx_part_kernel(
    const float* __restrict__ tokens,       // (B,N,H)
    const int*   __restrict__ window_start, // (B,)
    const float* __restrict__ ws_align,     // (B, ALN_STRIDE)
    float* __restrict__ ctx_part)           // (B, 4, H)
{
  const int b  = blockIdx.x;
  const int wq = blockIdx.y;
  const int t  = threadIdx.x;
  const int w0 = wq * 32;
  const int nW = (wq == 3) ? 33 : 32;

  __shared__ float sa[33];
  if (t < nW) sa[t] = ws_align[b * ALN_STRIDE + w0 + t];
  __syncthreads();

  const int ws = window_start[b];
  const float* Tp = tokens + (size_t)b * (NN * HH) + (size_t)(ws + w0) * HH + t;
  float acc = 0.f;
  #pragma unroll 8
  for (int w = 0; w < nW; ++w) acc += sa[w] * Tp[(size_t)w * HH];
  ctx_part[((b << 2) + wq) * HH + t] = acc;
}

// ---------------- Kernel C: reduce partials -> context ----------------
__global__ __launch_bounds__(256) void ctx_reduce_kernel(
    const float* __restrict__ ctx_part,     // (B, 4, H)
    float* __restrict__ out)                // context (B,H)
{
  const int b = blockIdx.x;
  const int t = threadIdx.x;
  const float* p = ctx_part + (size_t)(b << 2) * HH + t;
  out[b * HH + t] = p[0] + p[HH] + p[2 * HH] + p[3 * HH];
}

extern "C" void kernel_launch(void* const* d_in, const int* in_sizes, int n_in,
                              void* d_out, int out_size, void* d_ws, size_t ws_size,
                              hipStream_t stream) {
  const float* tokens       = (const float*)d_in[0];
  // d_in[1] = tokens_mask (bool) — recomputed from num_tokens, unused
  const float* token_keys   = (const float*)d_in[2];
  const int*   num_tokens   = (const int*)d_in[3];
  const float* query        = (const float*)d_in[4];
  const float* alignment    = (const float*)d_in[5];
  const float* cum_align    = (const float*)d_in[6];
  const int*   window_start = (const int*)d_in[7];
  const float* conv_w       = (const float*)d_in[8];
  const float* conv_b       = (const float*)d_in[9];

  float* ws_align = (float*)d_ws;                       // B * ALN_STRIDE
  float* ctx_part = ws_align + BB * ALN_STRIDE;         // B * 4 * HH

  score_kernel<<<BB, 1024, 0, stream>>>(token_keys, num_tokens, query,
                                        alignment, cum_align, window_start,
                                        conv_w, conv_b, (float*)d_out, ws_align);
  ctx_part_kernel<<<dim3(BB, 4), 256, 0, stream>>>(tokens, window_start,
                                                   ws_align, ctx_part);
  ctx_reduce_kernel<<<BB, 256, 0, stream>>>(ctx_part, (float*)d_out);
}

// Round 4
// 509.591 us; speedup vs baseline: 1.0245x; 1.0245x over previous
//
#include <hip/hip_runtime.h>
#include <math.h>

// Problem constants: B=512, N=600, H=256, K=9, WIN=129
#define BB   512
#define NN   600
#define HH   256
#define KS   9
#define WIN  129
#define PADW 4
#define PWIN 137           // WIN + 2*PAD
#define NP   608           // N + 2*PAD

// Fused single kernel. One block per batch, 1024 threads (16 waves).
// Plain __launch_bounds__(1024) -> VGPR cap 128, no forced-64 spill risk.
// Conv fold done via LDS staging (no per-thread register arrays).
__global__ __launch_bounds__(1024) void attn_kernel(
    const float* __restrict__ tokens,       // (B,N,H)
    const float* __restrict__ token_keys,   // (B,H,N)
    const int*   __restrict__ num_tokens,   // (B,)
    const float* __restrict__ query,        // (B,H)
    const float* __restrict__ alignment,    // (B,NP)
    const float* __restrict__ cum_align,    // (B,NP)
    const int*   __restrict__ window_start, // (B,)
    const float* __restrict__ conv_w,       // (H,2,K)
    const float* __restrict__ conv_b,       // (H,)
    float* __restrict__ out)
{
  const int b    = blockIdx.x;
  const int t    = threadIdx.x;
  const int lane = t & 63;
  const int wv   = t >> 6;            // 0..15

  __shared__ float sq[HH];            // query row (1 KB)
  __shared__ float scw[HH * 18];      // conv_w staged (18 KB)
  __shared__ float scb[HH];           // conv_b staged (1 KB)
  __shared__ float p0[PWIN], p1[PWIN];
  __shared__ float cred[19][8];       // conv-fold partials
  __shared__ float w128red[4];        // w=128 column dot partials
  __shared__ float sqc[19];           // folded conv scalars
  __shared__ float sS[8][130];        // per-h-group score partials
  __shared__ float salign[WIN];
  __shared__ int   cand[WIN];
  __shared__ __align__(16) float sctx[16][HH];  // context partials (16 KB)
  __shared__ float s_m, s_sum;
  __shared__ int   s_arg;

  const int ws = window_start[b];
  const int nt = num_tokens[b];
  const float* Kb = token_keys + (size_t)b * (HH * NN);

  // ---- Stage inputs to LDS ----
  float qreg = 0.f;
  if (t < HH) {
    qreg = query[b * HH + t];
    sq[t] = qreg;
    scb[t] = conv_b[t];
  }
  #pragma unroll
  for (int i = 0; i < 5; ++i) {
    int j = t + i * 1024;
    if (j < HH * 18) scw[j] = conv_w[j];
  }
  if (t < PWIN) {
    p0[t] = cum_align[b * NP + ws + t] * (1.0f / 1.5f) - 1.0f;
    p1[t] = alignment[b * NP + ws + t] * 2.0f - 1.0f;
  }
  __syncthreads();

  // ---- Conv fold: sqc[j] = sum_h q[h]*cw[h][j] (j<18), sqc[18]=sum q*cb ----
  // 152 threads: j = t>>3 (0..18), seg = t&7 -> 32-long h partial each.
  if (t < 152) {
    const int j = t >> 3, seg = t & 7;
    const int h0 = seg * 32;
    float a = 0.f;
    if (j < 18) {
      #pragma unroll 8
      for (int h = 0; h < 32; ++h) a += sq[h0 + h] * scw[(h0 + h) * 18 + j];
    } else {
      #pragma unroll 8
      for (int h = 0; h < 32; ++h) a += sq[h0 + h] * scb[h0 + h];
    }
    cred[j][seg] = a;
  }

  // ---- w=128 column dot (threads 0..255, thread t owns h=t) ----
  if (t < HH) {
    float v = qreg * Kb[(size_t)t * NN + ws + 128];
    #pragma unroll
    for (int off = 32; off; off >>= 1) v += __shfl_xor(v, off, 64);
    if (lane == 0) w128red[wv] = v;
  }

  // ---- Phase B: keys dot. wave v = (hh 0..7, wseg 0..1); 32-long h dot ----
  {
    const int hh   = wv & 7;
    const int wseg = wv >> 3;
    const int w    = wseg * 64 + lane;     // 0..127
    const float* Kp  = Kb + (size_t)(hh * 32) * NN + ws + w;
    const float* sqp = sq + hh * 32;
    float acc = 0.f;
    #pragma unroll 8
    for (int h = 0; h < 32; ++h) acc += sqp[h] * Kp[(size_t)h * NN];
    sS[hh][w] = acc;
  }
  __syncthreads();

  if (t < 19) {
    const float* c = cred[t];
    sqc[t] = ((c[0] + c[1]) + (c[2] + c[3])) + ((c[4] + c[5]) + (c[6] + c[7]));
  }
  __syncthreads();

  // ---- Score assembly (threads 0..128) ----
  float sc = 0.f;
  if (t < WIN) {
    float dot;
    if (t < 128) {
      dot = 0.f;
      #pragma unroll
      for (int g = 0; g < 8; ++g) dot += sS[g][t];
    } else {
      dot = w128red[0] + w128red[1] + w128red[2] + w128red[3];
    }
    float f = sqc[18];
    #pragma unroll
    for (int k = 0; k < KS; ++k) f += sqc[k] * p0[t + k] + sqc[9 + k] * p1[t + k];
    sc = (dot + f) * 0.0625f;                 // / sqrt(256)
    if (ws + t >= nt) sc = -INFINITY;
    salign[t] = sc;
  }
  __syncthreads();

  // ---- Softmax max + argmax + sum (wave 0 reductions) ----
  if (t < 64) {
    float m0 = fmaxf(salign[t], salign[t + 64]);
    if (t == 0) m0 = fmaxf(m0, salign[128]);
    #pragma unroll
    for (int off = 32; off; off >>= 1) m0 = fmaxf(m0, __shfl_xor(m0, off, 64));
    if (t == 0) s_m = m0;
  }
  __syncthreads();
  if (t < WIN) {
    float e = expf(sc - s_m);
    salign[t] = e;
    cand[t] = (sc == s_m) ? t : 0x7fffffff;   // first-index argmax
  }
  __syncthreads();
  if (t < 64) {
    float s0 = salign[t] + salign[t + 64] + ((t == 0) ? salign[128] : 0.f);
    int   c0 = min(cand[t], cand[t + 64]);
    if (t == 0) c0 = min(c0, cand[128]);
    #pragma unroll
    for (int off = 32; off; off >>= 1) {
      s0 += __shfl_xor(s0, off, 64);
      c0 = min(c0, __shfl_xor(c0, off, 64));
    }
    if (t == 0) { s_sum = s0; s_arg = c0; }
  }
  __syncthreads();
  const float inv = 1.0f / s_sum;
  if (t < WIN) salign[t] *= inv;
  __syncthreads();

  // ---- Output pointers ----
  float* out0 = out;                       // context     (B,H)
  float* out1 = out0 + BB * HH;            // unpadded    (B,N)
  float* out2 = out1 + BB * NN;            // full_align  (B,NP)
  float* out3 = out2 + BB * NP;            // cum+align   (B,NP)
  float* out4 = out3 + BB * NP;            // new_start   (B,) as float

  // ---- Phase C: context via float4. wave v covers w = v, v+16, ... ----
  {
    const float* Tb = tokens + (size_t)b * (NN * HH) + (size_t)ws * HH;
    float4 acc = make_float4(0.f, 0.f, 0.f, 0.f);
    #pragma unroll
    for (int i = 0; i < 8; ++i) {
      const int w = wv + 16 * i;            // 0..127 across waves
      const float a = salign[w];
      const float4 v4 = ((const float4*)(Tb + (size_t)w * HH))[lane];
      acc.x += a * v4.x; acc.y += a * v4.y; acc.z += a * v4.z; acc.w += a * v4.w;
    }
    if (wv == 0) {                          // tail w = 128
      const float a = salign[128];
      const float4 v4 = ((const float4*)(Tb + (size_t)128 * HH))[lane];
      acc.x += a * v4.x; acc.y += a * v4.y; acc.z += a * v4.z; acc.w += a * v4.w;
    }
    ((float4*)&sctx[wv][0])[lane] = acc;
  }
  __syncthreads();
  if (t < HH) {
    float c = 0.f;
    #pragma unroll
    for (int v = 0; v < 16; ++v) c += sctx[v][t];
    out0[b * HH + t] = c;
  }

  // ---- Scatter outputs (d_out is poisoned — write everything) ----
  if (t < NN) {
    float v = (t >= ws && t <= ws + 128) ? salign[t - ws] : 0.f;
    out1[b * NN + t] = v;
  }
  if (t < NP) {
    float v = (t >= ws + PADW && t <= ws + PADW + 128) ? salign[t - ws - PADW] : 0.f;
    out2[b * NP + t] = v;
    out3[b * NP + t] = v + cum_align[b * NP + t];
  }
  if (t == 0) {
    int jstar = ws + PADW + s_arg;
    int ns = jstar - (PWIN / 2);
    ns = max(ws, ns);
    ns = min(ns, nt - WIN);
    ns = max(ns, 0);
    out4[b] = (float)ns;
  }
}

extern "C" void kernel_launch(void* const* d_in, const int* in_sizes, int n_in,
                              void* d_out, int out_size, void* d_ws, size_t ws_size,
                              hipStream_t stream) {
  const float* tokens       = (const float*)d_in[0];
  // d_in[1] = tokens_mask (bool) — recomputed from num_tokens, unused
  const float* token_keys   = (const float*)d_in[2];
  const int*   num_tokens   = (const int*)d_in[3];
  const float* query        = (const float*)d_in[4];
  const float* alignment    = (const float*)d_in[5];
  const float* cum_align    = (const float*)d_in[6];
  const int*   window_start = (const int*)d_in[7];
  const float* conv_w       = (const float*)d_in[8];
  const float* conv_b       = (const float*)d_in[9];

  attn_kernel<<<BB, 1024, 0, stream>>>(tokens, token_keys, num_tokens, query,
                                       alignment, cum_align, window_start,
                                       conv_w, conv_b, (float*)d_out);
}